// Round 6
// baseline (1096.198 us; speedup 1.0000x reference)
//
#include <hip/hip_runtime.h>

// Round 6: kill the per-lane global gather (the real R4/R5 bottleneck).
//   Evidence: bucket_scan time invariant (347 vs 345 us) under a total change
//   of gather locality -> bound by gather SPLITS (64 lanes x 64 distinct lines
//   = 64 serial L1 transactions per wave gather), not by cache level.
// Fix: chunk=4096 atoms. LDS = acc[4][4096] (64K) + staged src charges[4][4096]
//   (64K), both channel-major (transposed) so per-lane LDS access is
//   bank-random (~2/bank, free). Entries sorted by (dest_chunk, src_chunk) =
//   2401 buckets via radix layout with ZERO global atomics:
//   count -> counts2d[block][bucket] -> column scan + block scan -> scatter.
// Entry = (src_global(18b) | dest_local(12b)<<18, w). w = 0.5/d.

#define CA_BITS 12
#define CHUNK 4096
#define NCHUNK 49                 // ceil(200000/4096)
#define NB (NCHUNK * NCHUNK)      // 2401
#define PPB 16384                 // pairs per count/scatter block
#define CS_BLOCK 1024
#define SCAN_BLOCK 1024
#define NSL 6                     // dest-region slices -> grid 49*6=294

// ---------- Pass 1: per-block bucket histogram (no global atomics) ----------
__global__ __launch_bounds__(CS_BLOCK) void count_pairs(
    const int2* __restrict__ idx, unsigned* __restrict__ counts2d, int npairs)
{
    __shared__ unsigned hist[NB];
    for (int b = threadIdx.x; b < NB; b += CS_BLOCK) hist[b] = 0;
    __syncthreads();
    const int p0 = blockIdx.x * PPB, p1 = min(p0 + PPB, npairs);
    for (int p = p0 + threadIdx.x; p < p1; p += CS_BLOCK) {
        int2 ij = idx[p];
        unsigned ci = (unsigned)ij.x >> CA_BITS;
        unsigned cj = (unsigned)ij.y >> CA_BITS;
        atomicAdd(&hist[ci * NCHUNK + cj], 1u);
        atomicAdd(&hist[cj * NCHUNK + ci], 1u);
    }
    __syncthreads();
    unsigned* row = counts2d + (size_t)blockIdx.x * NB;
    for (int b = threadIdx.x; b < NB; b += CS_BLOCK) row[b] = hist[b];
}

// ---------- Pass 2a: column scan over blocks (bucket-parallel) ----------
__global__ __launch_bounds__(256) void col_scan(
    const unsigned* __restrict__ counts2d, unsigned* __restrict__ base2d,
    unsigned* __restrict__ totals, int nblk)
{
    int b = blockIdx.x * 256 + threadIdx.x;
    if (b >= NB) return;
    unsigned run = 0;
    for (int k = 0; k < nblk; ++k) {
        unsigned v = counts2d[(size_t)k * NB + b];
        base2d[(size_t)k * NB + b] = run;
        run += v;
    }
    totals[b] = run;
}

// ---------- Pass 2b: exclusive scan of 2401 totals -> offsets ----------
__global__ __launch_bounds__(1024) void scan_offsets(
    const unsigned* __restrict__ totals, unsigned* __restrict__ offsets)
{
    __shared__ unsigned ts[1024];
    const int t = threadIdx.x;
    unsigned v[3], sum = 0;
#pragma unroll
    for (int q = 0; q < 3; ++q) {
        int b = t * 3 + q;
        v[q] = (b < NB) ? totals[b] : 0u;
        sum += v[q];
    }
    ts[t] = sum;
    __syncthreads();
    for (int d = 1; d < 1024; d <<= 1) {
        unsigned o = (t >= d) ? ts[t - d] : 0u;
        __syncthreads();
        ts[t] += o;
        __syncthreads();
    }
    unsigned ex = ts[t] - sum;
#pragma unroll
    for (int q = 0; q < 3; ++q) {
        int b = t * 3 + q;
        if (b < NB) offsets[b] = ex;
        ex += v[q];
    }
    if (t == 1023) offsets[NB] = ts[1023];
}

// ---------- Pass 3: scatter entries to exact positions ----------
__global__ __launch_bounds__(CS_BLOCK) void scatter_pairs(
    const int2* __restrict__ idx, const float* __restrict__ dist,
    uint2* __restrict__ entries, const unsigned* __restrict__ offsets,
    const unsigned* __restrict__ base2d, int npairs)
{
    __shared__ unsigned rankh[NB];
    __shared__ unsigned baseL[NB];
    const unsigned* brow = base2d + (size_t)blockIdx.x * NB;
    for (int b = threadIdx.x; b < NB; b += CS_BLOCK) {
        rankh[b] = 0u;
        baseL[b] = offsets[b] + brow[b];
    }
    __syncthreads();
    const int p0 = blockIdx.x * PPB, p1 = min(p0 + PPB, npairs);
    for (int p = p0 + threadIdx.x; p < p1; p += CS_BLOCK) {
        int2 ij = idx[p];
        float w = 0.5f / dist[p];
        unsigned ai = (unsigned)ij.x, aj = (unsigned)ij.y;
        unsigned ci = ai >> CA_BITS, cj = aj >> CA_BITS;
        unsigned b0 = ci * NCHUNK + cj, b1 = cj * NCHUNK + ci;
        unsigned wb = __float_as_uint(w);
        unsigned r0 = atomicAdd(&rankh[b0], 1u);
        entries[baseL[b0] + r0] = make_uint2(aj | ((ai & (CHUNK - 1)) << 18), wb);
        unsigned r1 = atomicAdd(&rankh[b1], 1u);
        entries[baseL[b1] + r1] = make_uint2(ai | ((aj & (CHUNK - 1)) << 18), wb);
    }
}

// ---------- Pass 4: LDS-staged scan (no global gathers) ----------
__global__ __launch_bounds__(SCAN_BLOCK) void scan_lds(
    const float4* __restrict__ charges, const uint2* __restrict__ entries,
    const unsigned* __restrict__ offsets, float* __restrict__ slabs, int natoms)
{
    extern __shared__ float lds[];     // [0,16384): acc ch-major; [16384,32768): staged charges
    const int c = blockIdx.x / NSL;
    const int s = blockIdx.x - c * NSL;
    for (int e = threadIdx.x; e < 4 * CHUNK; e += SCAN_BLOCK) lds[e] = 0.f;
    __syncthreads();

    const unsigned beg = offsets[c * NCHUNK];
    const unsigned cnt = offsets[(c + 1) * NCHUNK] - beg;
    const unsigned e0 = beg + (unsigned)((unsigned long long)cnt * s / NSL);
    const unsigned e1 = beg + (unsigned)((unsigned long long)cnt * (s + 1) / NSL);

    for (int b = 0; b < NCHUNK; ++b) {
        unsigned B0 = offsets[c * NCHUNK + b];
        unsigned B1 = offsets[c * NCHUNK + b + 1];
        unsigned r0 = max(B0, e0), r1 = min(B1, e1);
        if (r0 >= r1) continue;                 // uniform branch
        __syncthreads();                        // prior bucket done reading cs
        const int a0 = b << CA_BITS;
        for (int a = threadIdx.x; a < CHUNK; a += SCAN_BLOCK) {
            float4 q = (a0 + a < natoms) ? charges[a0 + a] : make_float4(0.f, 0.f, 0.f, 0.f);
            lds[4 * CHUNK + a]             = q.x;
            lds[4 * CHUNK + CHUNK + a]     = q.y;
            lds[4 * CHUNK + 2 * CHUNK + a] = q.z;
            lds[4 * CHUNK + 3 * CHUNK + a] = q.w;
        }
        __syncthreads();
        unsigned e = r0 + threadIdx.x;
        for (; e + 3u * SCAN_BLOCK < r1; e += 4u * SCAN_BLOCK) {
            uint2 en[4];
#pragma unroll
            for (int u = 0; u < 4; ++u) en[u] = entries[e + u * SCAN_BLOCK];
#pragma unroll
            for (int u = 0; u < 4; ++u) {
                float w = __uint_as_float(en[u].y);
                unsigned sl = en[u].x & (CHUNK - 1);
                unsigned dl = en[u].x >> 18;
                atomicAdd(&lds[dl],             lds[4 * CHUNK + sl] * w);
                atomicAdd(&lds[CHUNK + dl],     lds[4 * CHUNK + CHUNK + sl] * w);
                atomicAdd(&lds[2 * CHUNK + dl], lds[4 * CHUNK + 2 * CHUNK + sl] * w);
                atomicAdd(&lds[3 * CHUNK + dl], lds[4 * CHUNK + 3 * CHUNK + sl] * w);
            }
        }
        for (; e < r1; e += SCAN_BLOCK) {
            uint2 en = entries[e];
            float w = __uint_as_float(en.y);
            unsigned sl = en.x & (CHUNK - 1);
            unsigned dl = en.x >> 18;
            atomicAdd(&lds[dl],             lds[4 * CHUNK + sl] * w);
            atomicAdd(&lds[CHUNK + dl],     lds[4 * CHUNK + CHUNK + sl] * w);
            atomicAdd(&lds[2 * CHUNK + dl], lds[4 * CHUNK + 2 * CHUNK + sl] * w);
            atomicAdd(&lds[3 * CHUNK + dl], lds[4 * CHUNK + 3 * CHUNK + sl] * w);
        }
    }
    __syncthreads();

    const int c0 = c << CA_BITS;
    const int nv = min(CHUNK, natoms - c0);
    float4* dst = (float4*)(slabs + (size_t)blockIdx.x * (4 * CHUNK));
    for (int a = threadIdx.x; a < nv; a += SCAN_BLOCK)
        dst[a] = make_float4(lds[a], lds[CHUNK + a], lds[2 * CHUNK + a], lds[3 * CHUNK + a]);
}

// ---------- slab reduce ----------
template<int CH_ELEMS, int NS>
__global__ __launch_bounds__(256) void chunk_reduce(
    const float* __restrict__ ws, float* __restrict__ out, int total)
{
    int g = blockIdx.x * blockDim.x + threadIdx.x;
    if (g >= total) return;
    int c = g / CH_ELEMS;
    int local = g - c * CH_ELEMS;
    const float* p = ws + ((size_t)c * NS) * CH_ELEMS + local;
    float acc = 0.f;
#pragma unroll
    for (int s = 0; s < NS; ++s) acc += p[(size_t)s * CH_ELEMS];
    out[g] = acc;
}

// ---------- Fallback (R3): redundant chunk scan ----------
#define FB_BLOCK 1024
#define FB_NSL 10
#define FB_UNROLL 8
template<int CHUNK_ATOMS, bool USE_WS>
__global__ __launch_bounds__(FB_BLOCK) void chunk_scan(
    const float4* __restrict__ charges, const int2* __restrict__ idx,
    const float* __restrict__ dist, float* __restrict__ dest,
    int npairs, int natoms)
{
    constexpr int CH_ELEMS = CHUNK_ATOMS * 4;
    extern __shared__ float sm[];
    const int c  = blockIdx.x / FB_NSL;
    const int s  = blockIdx.x - c * FB_NSL;
    const int c0 = c * CHUNK_ATOMS;
    const int cn = min(CHUNK_ATOMS, natoms - c0);
    for (int e = threadIdx.x; e < CH_ELEMS; e += FB_BLOCK) sm[e] = 0.f;
    __syncthreads();
    const int p0 = (int)((long long)npairs * s       / FB_NSL);
    const int p1 = (int)((long long)npairs * (s + 1) / FB_NSL);
    const int nbatch = (p1 - p0) / (FB_BLOCK * FB_UNROLL);
    int p = p0 + threadIdx.x;
    for (int b = 0; b < nbatch; ++b, p += FB_BLOCK * FB_UNROLL) {
        int2 ij[FB_UNROLL]; float dd[FB_UNROLL];
#pragma unroll
        for (int u = 0; u < FB_UNROLL; ++u) { ij[u] = idx[p + u * FB_BLOCK]; dd[u] = dist[p + u * FB_BLOCK]; }
#pragma unroll
        for (int u = 0; u < FB_UNROLL; ++u) {
            unsigned li = (unsigned)(ij[u].x - c0), lj = (unsigned)(ij[u].y - c0);
            float w = 0.5f / dd[u];
            if (li < (unsigned)cn) {
                float4 cq = charges[ij[u].y]; float* bp = sm + li * 4;
                atomicAdd(bp + 0, cq.x * w); atomicAdd(bp + 1, cq.y * w);
                atomicAdd(bp + 2, cq.z * w); atomicAdd(bp + 3, cq.w * w);
            }
            if (lj < (unsigned)cn) {
                float4 cq = charges[ij[u].x]; float* bp = sm + lj * 4;
                atomicAdd(bp + 0, cq.x * w); atomicAdd(bp + 1, cq.y * w);
                atomicAdd(bp + 2, cq.z * w); atomicAdd(bp + 3, cq.w * w);
            }
        }
    }
    for (; p < p1; p += FB_BLOCK) {
        int2 ij = idx[p];
        unsigned li = (unsigned)(ij.x - c0), lj = (unsigned)(ij.y - c0);
        if (li < (unsigned)cn || lj < (unsigned)cn) {
            float w = 0.5f / dist[p];
            if (li < (unsigned)cn) {
                float4 cq = charges[ij.y]; float* bp = sm + li * 4;
                atomicAdd(bp + 0, cq.x * w); atomicAdd(bp + 1, cq.y * w);
                atomicAdd(bp + 2, cq.z * w); atomicAdd(bp + 3, cq.w * w);
            }
            if (lj < (unsigned)cn) {
                float4 cq = charges[ij.x]; float* bp = sm + lj * 4;
                atomicAdd(bp + 0, cq.x * w); atomicAdd(bp + 1, cq.y * w);
                atomicAdd(bp + 2, cq.z * w); atomicAdd(bp + 3, cq.w * w);
            }
        }
    }
    __syncthreads();
    const int nvalid = cn * 4;
    if (USE_WS) {
        float* dst = dest + (size_t)blockIdx.x * CH_ELEMS;
        for (int e = threadIdx.x; e < nvalid; e += FB_BLOCK) dst[e] = sm[e];
    } else {
        float* dst = dest + (size_t)c0 * 4;
        for (int e = threadIdx.x; e < nvalid; e += FB_BLOCK) atomicAdd(dst + e, sm[e]);
    }
}

extern "C" void kernel_launch(void* const* d_in, const int* in_sizes, int n_in,
                              void* d_out, int out_size, void* d_ws, size_t ws_size,
                              hipStream_t stream) {
    const float4* charges = (const float4*)d_in[0];
    const int2*   idx     = (const int2*)  d_in[1];
    const float*  dist    = (const float*) d_in[2];
    float*        out     = (float*)d_out;

    const int natoms = in_sizes[0] / 4;     // 200000
    const int npairs = in_sizes[2];         // 8000000
    const int total  = out_size;            // 800000

    int dev = 0;
    hipGetDevice(&dev);
    int maxShm = 0;
    hipDeviceGetAttribute(&maxShm, hipDeviceAttributeMaxSharedMemoryPerBlock, dev);
    const bool big = (maxShm >= 131072);

    const int nblk = (npairs + PPB - 1) / PPB;      // 489

    // ws layout
    const size_t o_offsets = 0;                                  // (NB+1)*4
    const size_t o_totals  = 16384;                              // NB*4
    const size_t o_counts  = 32768;
    const size_t c2_bytes  = ((size_t)nblk * NB * 4 + 255) & ~(size_t)255;
    const size_t o_base    = o_counts + c2_bytes;
    const size_t o_entries = o_base + c2_bytes;
    const size_t ent_bytes = ((size_t)2 * npairs * 8 + 255) & ~(size_t)255;
    const size_t o_slabs   = o_entries + ent_bytes;
    const size_t slab_bytes = (size_t)NCHUNK * NSL * (4 * CHUNK) * 4;  // 19.3 MB
    const size_t need      = o_slabs + slab_bytes;               // ~157 MB

    if (big && ws_size >= need && natoms <= NCHUNK * CHUNK && natoms <= (1 << 18)) {
        unsigned* offsets  = (unsigned*)((char*)d_ws + o_offsets);
        unsigned* totals   = (unsigned*)((char*)d_ws + o_totals);
        unsigned* counts2d = (unsigned*)((char*)d_ws + o_counts);
        unsigned* base2d   = (unsigned*)((char*)d_ws + o_base);
        uint2*    entries  = (uint2*)   ((char*)d_ws + o_entries);
        float*    slabs    = (float*)   ((char*)d_ws + o_slabs);

        count_pairs<<<nblk, CS_BLOCK, 0, stream>>>(idx, counts2d, npairs);
        col_scan<<<(NB + 255) / 256, 256, 0, stream>>>(counts2d, base2d, totals, nblk);
        scan_offsets<<<1, 1024, 0, stream>>>(totals, offsets);
        scatter_pairs<<<nblk, CS_BLOCK, 0, stream>>>(idx, dist, entries, offsets, base2d, npairs);
        hipFuncSetAttribute((const void*)scan_lds,
                            hipFuncAttributeMaxDynamicSharedMemorySize, 8 * CHUNK * 4);
        scan_lds<<<NCHUNK * NSL, SCAN_BLOCK, 8 * CHUNK * 4, stream>>>(
            charges, entries, offsets, slabs, natoms);
        chunk_reduce<4 * CHUNK, NSL><<<(total + 255) / 256, 256, 0, stream>>>(slabs, out, total);
    } else if (big) {
        constexpr int CA = 8192, CE = CA * 4;
        const int C = (natoms + CA - 1) / CA;
        const int grid = C * FB_NSL;
        const size_t ws_need = (size_t)grid * CE * sizeof(float);
        if (ws_size >= ws_need) {
            hipFuncSetAttribute((const void*)chunk_scan<CA, true>,
                                hipFuncAttributeMaxDynamicSharedMemorySize, CE * 4);
            chunk_scan<CA, true><<<grid, FB_BLOCK, CE * 4, stream>>>(
                charges, idx, dist, (float*)d_ws, npairs, natoms);
            chunk_reduce<CE, FB_NSL><<<(total + 255) / 256, 256, 0, stream>>>(
                (const float*)d_ws, out, total);
        } else {
            hipMemsetAsync(d_out, 0, (size_t)total * sizeof(float), stream);
            hipFuncSetAttribute((const void*)chunk_scan<CA, false>,
                                hipFuncAttributeMaxDynamicSharedMemorySize, CE * 4);
            chunk_scan<CA, false><<<grid, FB_BLOCK, CE * 4, stream>>>(
                charges, idx, dist, out, npairs, natoms);
        }
    } else {
        constexpr int CA = 4096, CE = CA * 4;
        const int C = (natoms + CA - 1) / CA;
        const int grid = C * FB_NSL;
        const size_t ws_need = (size_t)grid * CE * sizeof(float);
        if (ws_size >= ws_need) {
            chunk_scan<CA, true><<<grid, FB_BLOCK, CE * 4, stream>>>(
                charges, idx, dist, (float*)d_ws, npairs, natoms);
            chunk_reduce<CE, FB_NSL><<<(total + 255) / 256, 256, 0, stream>>>(
                (const float*)d_ws, out, total);
        } else {
            hipMemsetAsync(d_out, 0, (size_t)total * sizeof(float), stream);
            chunk_scan<CA, false><<<grid, FB_BLOCK, CE * 4, stream>>>(
                charges, idx, dist, out, npairs, natoms);
        }
    }
}

// Round 7
// 569.669 us; speedup vs baseline: 1.9243x; 1.9243x over previous
//
#include <hip/hip_runtime.h>

// Round 7: revert to R4 structure (best known: 595 us) + micro-opts.
//   Key R6 finding: per-entry scan cost ~13 cyc is INVARIANT across
//   gather-based (R4), src-local (R5) and LDS-staged (R6) scans ->
//   bound by the 4 random ds_add_f32/entry + dependent-op issue, not caches.
//   So: keep R4's 25-bucket sort + 128KiB-LDS chunk scan (grid 250 <= 256),
//   and optimize the cheap stuff:
//   - count: int4 loads + 4-way replicated LDS hist (same-address atomic relief)
//   - scatter: PPT 8 + replicated hist with per-replica bases (exact ranks)
//   - scan: uint4 entry loads (2 entries/instr), 8-entry batches
//   - reduce: float4
// Entry = (other_idx(18b) | dest_local(13b)<<18, w=0.5/d).

#define BLOCK 1024
#define NSLICES 10
#define CT_BLOCK 256
#define SC_BLOCK 256
#define SC_PPT 8
#define CA_BITS 13        // chunk = 8192 atoms
#define NCHUNK 25
#define FB_NSL 10
#define FB_UNROLL 8

// ---------------- Pass 0: count entries per bucket (replicated hist) --------
__global__ __launch_bounds__(CT_BLOCK) void bucket_count(
    const int4* __restrict__ idx2, unsigned* __restrict__ counts, int npairs)
{
    __shared__ unsigned hist[NCHUNK * 4];
    for (int b = threadIdx.x; b < NCHUNK * 4; b += CT_BLOCK) hist[b] = 0;
    __syncthreads();
    const int n4 = npairs >> 1;                  // int4 = 2 pairs
    const int r = threadIdx.x & 3;
    const int stride = gridDim.x * CT_BLOCK;
    for (int q = blockIdx.x * CT_BLOCK + threadIdx.x; q < n4; q += stride) {
        int4 v = idx2[q];
        atomicAdd(&hist[(((unsigned)v.x >> CA_BITS) << 2) + r], 1u);
        atomicAdd(&hist[(((unsigned)v.y >> CA_BITS) << 2) + r], 1u);
        atomicAdd(&hist[(((unsigned)v.z >> CA_BITS) << 2) + r], 1u);
        atomicAdd(&hist[(((unsigned)v.w >> CA_BITS) << 2) + r], 1u);
    }
    // odd tail pair (npairs odd): one thread globally
    if ((npairs & 1) && blockIdx.x == 0 && threadIdx.x == 0) {
        const int2* idx = (const int2*)idx2;
        int2 ij = idx[npairs - 1];
        atomicAdd(&counts[(unsigned)ij.x >> CA_BITS], 1u);
        atomicAdd(&counts[(unsigned)ij.y >> CA_BITS], 1u);
    }
    __syncthreads();
    for (int b = threadIdx.x; b < NCHUNK; b += CT_BLOCK) {
        unsigned t = hist[4 * b] + hist[4 * b + 1] + hist[4 * b + 2] + hist[4 * b + 3];
        if (t) atomicAdd(&counts[b], t);
    }
}

// ---------------- prefix sum (25 elements) ----------------
__global__ void bucket_prefix(const unsigned* __restrict__ counts,
                              unsigned* __restrict__ offsets,
                              unsigned* __restrict__ cursors, int nbuckets)
{
    if (threadIdx.x == 0 && blockIdx.x == 0) {
        unsigned acc = 0;
        for (int b = 0; b < nbuckets; ++b) {
            offsets[b] = acc; cursors[b] = acc; acc += counts[b];
        }
        offsets[nbuckets] = acc;
    }
}

// ---------------- Pass A: scatter entries (replicated hist, exact ranks) ----
__global__ __launch_bounds__(SC_BLOCK) void bucket_scatter(
    const int2*  __restrict__ idx, const float* __restrict__ dist,
    uint2* __restrict__ entries, unsigned* __restrict__ cursors, int npairs)
{
    __shared__ unsigned hist[NCHUNK * 4];
    __shared__ unsigned rbase[NCHUNK * 4];
    for (int b = threadIdx.x; b < NCHUNK * 4; b += SC_BLOCK) hist[b] = 0;
    __syncthreads();

    const int p0 = blockIdx.x * (SC_BLOCK * SC_PPT) + threadIdx.x;
    const unsigned r = threadIdx.x & 3;
    unsigned key[2 * SC_PPT];
    unsigned brk[2 * SC_PPT];       // slot(7b: b*4+r) | rank<<7
    float    wv[SC_PPT];

#pragma unroll
    for (int k = 0; k < SC_PPT; ++k) {
        int p = p0 + k * SC_BLOCK;
        if (p < npairs) {
            int2 ij = idx[p];
            wv[k] = 0.5f / dist[p];
            unsigned s0 = (((unsigned)ij.x >> CA_BITS) << 2) + r;
            unsigned s1 = (((unsigned)ij.y >> CA_BITS) << 2) + r;
            key[2 * k]     = (unsigned)ij.y | (((unsigned)ij.x & ((1u << CA_BITS) - 1)) << 18);
            brk[2 * k]     = s0 | (atomicAdd(&hist[s0], 1u) << 7);
            key[2 * k + 1] = (unsigned)ij.x | (((unsigned)ij.y & ((1u << CA_BITS) - 1)) << 18);
            brk[2 * k + 1] = s1 | (atomicAdd(&hist[s1], 1u) << 7);
        } else {
            brk[2 * k] = brk[2 * k + 1] = 0xFFFFFFFFu;
        }
    }
    __syncthreads();
    if (threadIdx.x < NCHUNK) {
        int b = threadIdx.x;
        unsigned h0 = hist[4 * b], h1 = hist[4 * b + 1], h2 = hist[4 * b + 2], h3 = hist[4 * b + 3];
        unsigned tot = h0 + h1 + h2 + h3;
        unsigned g = tot ? atomicAdd(&cursors[b], tot) : 0u;
        rbase[4 * b]     = g;
        rbase[4 * b + 1] = g + h0;
        rbase[4 * b + 2] = g + h0 + h1;
        rbase[4 * b + 3] = g + h0 + h1 + h2;
    }
    __syncthreads();

#pragma unroll
    for (int k = 0; k < SC_PPT; ++k) {
        if (brk[2 * k] != 0xFFFFFFFFu) {
            unsigned wb = __float_as_uint(wv[k]);
            entries[rbase[brk[2 * k] & 127u] + (brk[2 * k] >> 7)] =
                make_uint2(key[2 * k], wb);
            entries[rbase[brk[2 * k + 1] & 127u] + (brk[2 * k + 1] >> 7)] =
                make_uint2(key[2 * k + 1], wb);
        }
    }
}

// ---------------- Pass B: chunk scan, uint4 entry loads ----------------
template<int CHUNK_ATOMS>
__global__ __launch_bounds__(BLOCK) void bucket_scan(
    const float4* __restrict__ charges, const uint2* __restrict__ entries,
    const unsigned* __restrict__ offsets, float* __restrict__ slabs,
    int natoms)
{
    constexpr int CH_ELEMS = CHUNK_ATOMS * 4;
    extern __shared__ float sm[];

    const int c  = blockIdx.x / NSLICES;
    const int s  = blockIdx.x - c * NSLICES;
    for (int e = threadIdx.x; e < CH_ELEMS; e += BLOCK) sm[e] = 0.f;
    __syncthreads();

    const unsigned beg = offsets[c];
    const unsigned cnt = offsets[c + 1] - beg;
    const unsigned e0  = beg + (unsigned)((unsigned long long)cnt * s       / NSLICES);
    const unsigned e1  = beg + (unsigned)((unsigned long long)cnt * (s + 1) / NSLICES);

    auto process = [&](uint2 en) {
        float4 cq = charges[en.x & 0x3FFFFu];
        float w = __uint_as_float(en.y);
        float* bp = sm + (en.x >> 18) * 4;
        atomicAdd(bp + 0, cq.x * w);
        atomicAdd(bp + 1, cq.y * w);
        atomicAdd(bp + 2, cq.z * w);
        atomicAdd(bp + 3, cq.w * w);
    };

    // head: align entry index to even for uint4 loads
    const unsigned e0a = min(e1, (e0 + 1u) & ~1u);
    for (unsigned e = e0 + threadIdx.x; e < e0a; e += BLOCK) process(entries[e]);

    const uint4* ent4 = (const uint4*)entries;
    const unsigned base = e0a >> 1;            // uint4 index
    const unsigned n4   = (e1 - e0a) >> 1;     // number of uint4s (each = 2 entries)
    const unsigned nb   = n4 / (BLOCK * 4);    // 8 entries per thread per batch

    unsigned q = base + threadIdx.x;
    for (unsigned b = 0; b < nb; ++b, q += BLOCK * 4) {
        uint4 E[4];
#pragma unroll
        for (int u = 0; u < 4; ++u) E[u] = ent4[q + u * BLOCK];
        float4 cq[8];
#pragma unroll
        for (int u = 0; u < 4; ++u) {
            cq[2 * u]     = charges[E[u].x & 0x3FFFFu];
            cq[2 * u + 1] = charges[E[u].z & 0x3FFFFu];
        }
#pragma unroll
        for (int u = 0; u < 4; ++u) {
            float w0 = __uint_as_float(E[u].y);
            float* b0 = sm + (E[u].x >> 18) * 4;
            atomicAdd(b0 + 0, cq[2 * u].x * w0);
            atomicAdd(b0 + 1, cq[2 * u].y * w0);
            atomicAdd(b0 + 2, cq[2 * u].z * w0);
            atomicAdd(b0 + 3, cq[2 * u].w * w0);
            float w1 = __uint_as_float(E[u].w);
            float* b1 = sm + (E[u].z >> 18) * 4;
            atomicAdd(b1 + 0, cq[2 * u + 1].x * w1);
            atomicAdd(b1 + 1, cq[2 * u + 1].y * w1);
            atomicAdd(b1 + 2, cq[2 * u + 1].z * w1);
            atomicAdd(b1 + 3, cq[2 * u + 1].w * w1);
        }
    }
    // uint4 tail
    for (unsigned q2 = base + nb * (BLOCK * 4) + threadIdx.x; q2 < base + n4; q2 += BLOCK) {
        uint4 E = ent4[q2];
        process(make_uint2(E.x, E.y));
        process(make_uint2(E.z, E.w));
    }
    // odd final entry
    for (unsigned e = e0a + 2 * n4 + threadIdx.x; e < e1; e += BLOCK) process(entries[e]);
    __syncthreads();

    const int c0 = c * CHUNK_ATOMS;
    const int nvalid = min(CHUNK_ATOMS, natoms - c0) * 4;
    float* dst = slabs + (size_t)blockIdx.x * CH_ELEMS;
    for (int e2 = threadIdx.x; e2 < nvalid; e2 += BLOCK) dst[e2] = sm[e2];
}

// ---------------- slab reduce (float4) ----------------
template<int CH_ELEMS, int NS>
__global__ __launch_bounds__(256) void chunk_reduce(
    const float4* __restrict__ ws, float4* __restrict__ out, int total4)
{
    int g = blockIdx.x * blockDim.x + threadIdx.x;
    if (g >= total4) return;
    constexpr int CH4 = CH_ELEMS / 4;
    int c = g / CH4;
    int local = g - c * CH4;
    const float4* p = ws + ((size_t)c * NS) * CH4 + local;
    float4 acc = make_float4(0.f, 0.f, 0.f, 0.f);
#pragma unroll
    for (int s = 0; s < NS; ++s) {
        float4 v = p[(size_t)s * CH4];
        acc.x += v.x; acc.y += v.y; acc.z += v.z; acc.w += v.w;
    }
    out[g] = acc;
}

// ---------------- Fallback (R3): redundant chunk scan ----------------
template<int CHUNK_ATOMS, bool USE_WS>
__global__ __launch_bounds__(BLOCK) void chunk_scan(
    const float4* __restrict__ charges, const int2* __restrict__ idx,
    const float* __restrict__ dist, float* __restrict__ dest,
    int npairs, int natoms)
{
    constexpr int CH_ELEMS = CHUNK_ATOMS * 4;
    extern __shared__ float sm[];
    const int c  = blockIdx.x / FB_NSL;
    const int s  = blockIdx.x - c * FB_NSL;
    const int c0 = c * CHUNK_ATOMS;
    const int cn = min(CHUNK_ATOMS, natoms - c0);
    for (int e = threadIdx.x; e < CH_ELEMS; e += BLOCK) sm[e] = 0.f;
    __syncthreads();
    const int p0 = (int)((long long)npairs * s       / FB_NSL);
    const int p1 = (int)((long long)npairs * (s + 1) / FB_NSL);
    const int nbatch = (p1 - p0) / (BLOCK * FB_UNROLL);
    int p = p0 + threadIdx.x;
    for (int b = 0; b < nbatch; ++b, p += BLOCK * FB_UNROLL) {
        int2 ij[FB_UNROLL]; float dd[FB_UNROLL];
#pragma unroll
        for (int u = 0; u < FB_UNROLL; ++u) { ij[u] = idx[p + u * BLOCK]; dd[u] = dist[p + u * BLOCK]; }
#pragma unroll
        for (int u = 0; u < FB_UNROLL; ++u) {
            unsigned li = (unsigned)(ij[u].x - c0), lj = (unsigned)(ij[u].y - c0);
            float w = 0.5f / dd[u];
            if (li < (unsigned)cn) {
                float4 cq = charges[ij[u].y]; float* bp = sm + li * 4;
                atomicAdd(bp + 0, cq.x * w); atomicAdd(bp + 1, cq.y * w);
                atomicAdd(bp + 2, cq.z * w); atomicAdd(bp + 3, cq.w * w);
            }
            if (lj < (unsigned)cn) {
                float4 cq = charges[ij[u].x]; float* bp = sm + lj * 4;
                atomicAdd(bp + 0, cq.x * w); atomicAdd(bp + 1, cq.y * w);
                atomicAdd(bp + 2, cq.z * w); atomicAdd(bp + 3, cq.w * w);
            }
        }
    }
    for (; p < p1; p += BLOCK) {
        int2 ij = idx[p];
        unsigned li = (unsigned)(ij.x - c0), lj = (unsigned)(ij.y - c0);
        if (li < (unsigned)cn || lj < (unsigned)cn) {
            float w = 0.5f / dist[p];
            if (li < (unsigned)cn) {
                float4 cq = charges[ij.y]; float* bp = sm + li * 4;
                atomicAdd(bp + 0, cq.x * w); atomicAdd(bp + 1, cq.y * w);
                atomicAdd(bp + 2, cq.z * w); atomicAdd(bp + 3, cq.w * w);
            }
            if (lj < (unsigned)cn) {
                float4 cq = charges[ij.x]; float* bp = sm + lj * 4;
                atomicAdd(bp + 0, cq.x * w); atomicAdd(bp + 1, cq.y * w);
                atomicAdd(bp + 2, cq.z * w); atomicAdd(bp + 3, cq.w * w);
            }
        }
    }
    __syncthreads();
    const int nvalid = cn * 4;
    if (USE_WS) {
        float* dst = dest + (size_t)blockIdx.x * CH_ELEMS;
        for (int e = threadIdx.x; e < nvalid; e += BLOCK) dst[e] = sm[e];
    } else {
        float* dst = dest + (size_t)c0 * 4;
        for (int e = threadIdx.x; e < nvalid; e += BLOCK) atomicAdd(dst + e, sm[e]);
    }
}

extern "C" void kernel_launch(void* const* d_in, const int* in_sizes, int n_in,
                              void* d_out, int out_size, void* d_ws, size_t ws_size,
                              hipStream_t stream) {
    const float4* charges = (const float4*)d_in[0];
    const int2*   idx     = (const int2*)  d_in[1];
    const float*  dist    = (const float*) d_in[2];
    float*        out     = (float*)d_out;

    const int natoms = in_sizes[0] / 4;     // 200000
    const int npairs = in_sizes[2];         // 8000000
    const int total  = out_size;            // 800000

    int dev = 0;
    hipGetDevice(&dev);
    int maxShm = 0;
    hipDeviceGetAttribute(&maxShm, hipDeviceAttributeMaxSharedMemoryPerBlock, dev);
    const bool big = (maxShm >= 131072);

    constexpr int CA = 8192, CE = CA * 4;
    const int C    = (natoms + CA - 1) / CA;       // 25
    const int grid = C * NSLICES;                  // 250

    const size_t ENT_OFF    = 1024;
    const size_t ent_bytes  = (size_t)2 * npairs * sizeof(uint2);  // 128 MB
    size_t slab_off         = (ENT_OFF + ent_bytes + 255) & ~(size_t)255;
    const size_t slab_bytes = (size_t)grid * CE * sizeof(float);   // 32.8 MB
    const size_t need       = slab_off + slab_bytes;

    if (big && ws_size >= need && natoms <= (1 << 18) && C == NCHUNK && (total & 3) == 0) {
        unsigned* counts  = (unsigned*)d_ws;               // [25]
        unsigned* offsets = (unsigned*)((char*)d_ws + 256);// [26]
        unsigned* cursors = (unsigned*)((char*)d_ws + 512);// [25]
        uint2*    entries = (uint2*)((char*)d_ws + ENT_OFF);
        float*    slabs   = (float*)((char*)d_ws + slab_off);

        hipMemsetAsync(d_ws, 0, 1024, stream);
        bucket_count<<<1024, CT_BLOCK, 0, stream>>>((const int4*)idx, counts, npairs);
        bucket_prefix<<<1, 32, 0, stream>>>(counts, offsets, cursors, C);
        const int sc_grid = (npairs + SC_BLOCK * SC_PPT - 1) / (SC_BLOCK * SC_PPT);
        bucket_scatter<<<sc_grid, SC_BLOCK, 0, stream>>>(idx, dist, entries, cursors, npairs);
        hipFuncSetAttribute((const void*)bucket_scan<CA>,
                            hipFuncAttributeMaxDynamicSharedMemorySize, CE * 4);
        bucket_scan<CA><<<grid, BLOCK, CE * 4, stream>>>(charges, entries, offsets, slabs, natoms);
        chunk_reduce<CE, NSLICES><<<(total / 4 + 255) / 256, 256, 0, stream>>>(
            (const float4*)slabs, (float4*)out, total / 4);
    } else if (big) {
        const size_t ws_need = (size_t)grid * CE * sizeof(float);
        if (ws_size >= ws_need && (total & 3) == 0) {
            hipFuncSetAttribute((const void*)chunk_scan<CA, true>,
                                hipFuncAttributeMaxDynamicSharedMemorySize, CE * 4);
            chunk_scan<CA, true><<<grid, BLOCK, CE * 4, stream>>>(
                charges, idx, dist, (float*)d_ws, npairs, natoms);
            chunk_reduce<CE, FB_NSL><<<(total / 4 + 255) / 256, 256, 0, stream>>>(
                (const float4*)d_ws, (float4*)out, total / 4);
        } else {
            hipMemsetAsync(d_out, 0, (size_t)total * sizeof(float), stream);
            hipFuncSetAttribute((const void*)chunk_scan<CA, false>,
                                hipFuncAttributeMaxDynamicSharedMemorySize, CE * 4);
            chunk_scan<CA, false><<<grid, BLOCK, CE * 4, stream>>>(
                charges, idx, dist, out, npairs, natoms);
        }
    } else {
        constexpr int CA2 = 4096, CE2 = CA2 * 4;
        const int C2 = (natoms + CA2 - 1) / CA2;
        const int grid2 = C2 * FB_NSL;
        const size_t ws_need = (size_t)grid2 * CE2 * sizeof(float);
        if (ws_size >= ws_need && (total & 3) == 0) {
            chunk_scan<CA2, true><<<grid2, BLOCK, CE2 * 4, stream>>>(
                charges, idx, dist, (float*)d_ws, npairs, natoms);
            chunk_reduce<CE2, FB_NSL><<<(total / 4 + 255) / 256, 256, 0, stream>>>(
                (const float4*)d_ws, (float4*)out, total / 4);
        } else {
            hipMemsetAsync(d_out, 0, (size_t)total * sizeof(float), stream);
            chunk_scan<CA2, false><<<grid2, BLOCK, CE2 * 4, stream>>>(
                charges, idx, dist, out, npairs, natoms);
        }
    }
}